// Round 2
// baseline (310.173 us; speedup 1.0000x reference)
//
#include <hip/hip_runtime.h>
#include <math.h>

#define HH 512
#define WW 1024
#define HWSZ (HH*WW)
#define BB 4
#define TY 8
#define KSIG 11.541560327111707f   /* 8*log2(e) */
#define DD_OFF (BB*3*HWSZ)

// offsets with ry^2+rx^2 > 49 dropped (sigma <= 1.9e-4, never in-circle)
// -> max |ry| per |rx|:
__device__ __constant__ int c_dummy; // (keep TU non-empty of constants)

template<bool EDGE>
__global__ __launch_bounds__(256)
void bokeh_kernel(const float* __restrict__ img,
                  const float* __restrict__ defo,
                  float* __restrict__ out)
{
    // TAB[ax][ry+6] = (D, D*KSIG), D = fp32(sqrt(ry^2+ax^2)) correctly rounded
    __shared__ float2 TAB[7][13];
    {
        const int t = threadIdx.x;
        if (t < 91) {
            const int ax = t / 13;
            const int ry = t - ax*13 - 6;
            const float D = (float)sqrt((double)(ry*ry + ax*ax));
            TAB[ax][ry+6] = make_float2(D, D*KSIG);
        }
    }
    __syncthreads();

    const int lane = threadIdx.x & 63;
    const int wv   = threadIdx.x >> 6;
    int bx;
    if (EDGE) bx = blockIdx.x ? (WW/64 - 1) : 0;   // cols [0,63] and [960,1023]
    else      bx = blockIdx.x + 1;                  // interior cols [64,959]
    const int x  = bx*64 + lane;
    const int y0 = blockIdx.y*(4*TY) + wv*TY;
    const int b  = blockIdx.z;

    const float* __restrict__ dP = defo + (size_t)b*HWSZ;
    const float* __restrict__ c0 = img + (size_t)(b*3+0)*HWSZ;
    const float* __restrict__ c1 = img + (size_t)(b*3+1)*HWSZ;
    const float* __restrict__ c2 = img + (size_t)(b*3+2)*HWSZ;

    float aW[TY], aR[TY], aG[TY], aB[TY], aD[TY];
#pragma unroll
    for (int k=0;k<TY;++k){aW[k]=0.f;aR[k]=0.f;aG[k]=0.f;aB[k]=0.f;aD[k]=-1e30f;}

    constexpr int AYM[7] = {6,6,6,6,6,4,3};   // max |ry| per |rx| (r^2 cut)

    for (int ryy = -6; ryy <= TY+5; ++ryy) {      // source rows
        const int sy = y0 + ryy;
        if ((unsigned)sy >= (unsigned)HH) continue;   // uniform skip (zero pad)
        const int rb = sy*WW + x;
        const float* __restrict__ pd = dP + rb;
        const float* __restrict__ p0 = c0 + rb;
        const float* __restrict__ p1 = c1 + rb;
        const float* __restrict__ p2 = c2 + rb;
#pragma unroll
        for (int rx = -6; rx <= 6; ++rx) {
            constexpr int RXA[13] = {6,5,4,3,2,1,0,1,2,3,4,5,6};
            const int ax  = RXA[rx+6];
            const int aym = AYM[ax];
            float d, i0, i1, i2;
            if (EDGE) {
                const int col = x + rx;
                const bool valid = (unsigned)col < (unsigned)WW;
                const int cc  = col < 0 ? 0 : (col > WW-1 ? WW-1 : col);
                const int cof = cc - x;           // clamped offset
                d = pd[cof]; i0 = p0[cof]; i1 = p1[cof]; i2 = p2[cof];
                d = valid ? d : 0.0f;             // r=0 -> w ~ 3e-30, no circle
            } else {
                d = pd[rx]; i0 = p0[rx]; i1 = p1[rx]; i2 = p2[rx];
            }
            const float r    = fabsf(d);
            const float ivr  = __builtin_amdgcn_rcpf(fmaxf(r*r, 1.0f));
            const float rK   = r * KSIG;
            const float dint = truncf(d);         // == (float)(int)defocus
#pragma unroll
            for (int k = 0; k < TY; ++k) {
                const int ry = ryy - k;           // wave-uniform
                if ((unsigned)(ry + aym) > (unsigned)(2*aym)) continue;
                const float2 DDv = TAB[ax][ry + 6];   // broadcast ds_read_b64
                const float e   = __builtin_amdgcn_exp2f(DDv.y - rK);
                const float w   = __builtin_amdgcn_rcpf(1.0f + e) * ivr;
                aW[k] += w;
                aR[k] = fmaf(w, i0, aR[k]);
                aG[k] = fmaf(w, i1, aG[k]);
                aB[k] = fmaf(w, i2, aB[k]);
                aD[k] = fmaxf(aD[k], (DDv.x <= r) ? dint : -1e30f);
            }
        }
    }

#pragma unroll
    for (int k=0;k<TY;++k) {
        const int y = y0 + k;
        const float inv = __builtin_amdgcn_rcpf(aW[k]);  // aW >= ~0.0139 always
        const size_t o = (size_t)y*WW + x;
        out[(size_t)(b*3+0)*HWSZ + o] = aR[k]*inv;
        out[(size_t)(b*3+1)*HWSZ + o] = aG[k]*inv;
        out[(size_t)(b*3+2)*HWSZ + o] = aB[k]*inv;
        out[DD_OFF + (size_t)b*HWSZ + o] = aD[k];
    }
}

extern "C" void kernel_launch(void* const* d_in, const int* in_sizes, int n_in,
                              void* d_out, int out_size, void* d_ws, size_t ws_size,
                              hipStream_t stream)
{
    const float* img  = (const float*)d_in[0];
    const float* defo = (const float*)d_in[1];
    float* out = (float*)d_out;
    bokeh_kernel<false><<<dim3(WW/64 - 2, HH/(4*TY), BB), dim3(256,1,1), 0, stream>>>(img, defo, out);
    bokeh_kernel<true ><<<dim3(2,        HH/(4*TY), BB), dim3(256,1,1), 0, stream>>>(img, defo, out);
}

// Round 3
// 173.010 us; speedup vs baseline: 1.7928x; 1.7928x over previous
//
#include <hip/hip_runtime.h>
#include <math.h>

#define HH 512
#define WW 1024
#define HWSZ (HH*WW)
#define BB 4
#define TY 8
#define KSIG 11.541560327111707f   /* 8*log2(e) */
#define DD_OFF (BB*3*HWSZ)

// Evaluate one group of source columns (compile-time rx offsets) for one
// source row against this thread's TY output rows. All j/k indexing is
// compile-time (full unroll) -> arrays stay in registers.
template<int... RX>
__device__ __forceinline__ void group_eval(
    const float* __restrict__ pd, const float* __restrict__ p0,
    const float* __restrict__ p1, const float* __restrict__ p2,
    int x, bool edge, int ryy, const float2 (*TT)[8],
    float* aW, float* aR, float* aG, float* aB, float* aD)
{
    constexpr int N = sizeof...(RX);
    constexpr int rxs[N] = { RX... };

    float d[N], i0[N], i1[N], i2[N];
#pragma unroll
    for (int j = 0; j < N; ++j) {
        const int rx = rxs[j];
        if (edge) {
            const int col = x + rx;
            const bool valid = (unsigned)col < (unsigned)WW;
            const int cc  = col < 0 ? 0 : (col > WW-1 ? WW-1 : col);
            const int cof = cc - x;                 // clamped (safe) offset
            float dv = pd[cof];
            d[j]  = valid ? dv : 0.0f;              // OOB: r=0 -> w<=3.4e-4, no circle
            i0[j] = p0[cof]; i1[j] = p1[cof]; i2[j] = p2[cof];
        } else {
            d[j] = pd[rx]; i0[j] = p0[rx]; i1[j] = p1[rx]; i2[j] = p2[rx];
        }
    }
    float r[N], rk[N], rr[N], di[N];
#pragma unroll
    for (int j = 0; j < N; ++j) {
        r[j]  = fabsf(d[j]);
        rr[j] = fmaxf(r[j]*r[j], 1.0f);
        rk[j] = r[j]*KSIG;
        di[j] = truncf(d[j]);                       // == (float)(int)defocus
    }
#pragma unroll
    for (int k = 0; k < TY; ++k) {
        const int ry = ryy - k;                     // wave-uniform
        const unsigned ay = (unsigned)(ry < 0 ? -ry : ry);
        if (ay > 6u) continue;                      // uniform skip
        const float2* row = TT[ry + 6];
#pragma unroll
        for (int j = 0; j < N; ++j) {
            const int rx = rxs[j];
            const int ax = rx < 0 ? -rx : rx;
            const unsigned aym = (ax <= 4) ? 6u : (ax == 5 ? 4u : 3u); // r^2<=49 cut
            if (ay <= aym) {
                const float2 DDv = row[ax];         // broadcast ds_read_b64
                const float e = __builtin_amdgcn_exp2f(DDv.y - rk[j]);
                const float w = __builtin_amdgcn_rcpf(fmaf(e, rr[j], rr[j]));
                aW[k] += w;
                aR[k] = fmaf(w, i0[j], aR[k]);
                aG[k] = fmaf(w, i1[j], aG[k]);
                aB[k] = fmaf(w, i2[j], aB[k]);
                aD[k] = fmaxf(aD[k], (DDv.x <= r[j]) ? di[j] : -1e30f);
            }
        }
    }
}

__global__ __launch_bounds__(256, 4)
void bokeh_kernel(const float* __restrict__ img,
                  const float* __restrict__ defo,
                  float* __restrict__ out)
{
    // TT[ry+6][ax] = (D, D*KSIG), D = fp32(sqrt(ry^2+ax^2)) correctly rounded
    __shared__ float2 TT[13][8];
    {
        const int t = threadIdx.x;
        if (t < 13*8) {
            const int row = t >> 3, ax = t & 7;
            float D = 1e30f, DK = 1e30f;
            if (ax < 7) {
                const int ry = row - 6;
                D = (float)sqrt((double)(ry*ry + ax*ax));
                DK = D * KSIG;
            }
            TT[row][ax] = make_float2(D, DK);
        }
    }
    __syncthreads();

    const int lane = threadIdx.x & 63;
    const int wv   = threadIdx.x >> 6;
    const int bx   = blockIdx.x;
    const int x    = bx*64 + lane;                 // lane = x -> coalesced
    const int y0   = blockIdx.y*(4*TY) + wv*TY;    // 8 output rows per thread
    const int b    = blockIdx.z;
    const bool edge = (bx == 0) || (bx == WW/64 - 1);   // wave-uniform

    const float* __restrict__ dP = defo + (size_t)b*HWSZ;
    const float* __restrict__ c0 = img + (size_t)(b*3+0)*HWSZ;
    const float* __restrict__ c1 = img + (size_t)(b*3+1)*HWSZ;
    const float* __restrict__ c2 = img + (size_t)(b*3+2)*HWSZ;

    float aW[TY], aR[TY], aG[TY], aB[TY], aD[TY];
#pragma unroll
    for (int k=0;k<TY;++k){aW[k]=0.f;aR[k]=0.f;aG[k]=0.f;aB[k]=0.f;aD[k]=-1e30f;}

#pragma unroll 1
    for (int ryy = -6; ryy <= TY+5; ++ryy) {       // source rows (runtime loop)
        const int sy = y0 + ryy;
        if ((unsigned)sy >= (unsigned)HH) continue;    // uniform (zero pad)
        const int rb = sy*WW + x;
        const float* __restrict__ pd = dP + rb;
        const float* __restrict__ p0 = c0 + rb;
        const float* __restrict__ p1 = c1 + rb;
        const float* __restrict__ p2 = c2 + rb;
        group_eval<-6,-5,-4,-3,-2>(pd,p0,p1,p2,x,edge,ryy,TT,aW,aR,aG,aB,aD);
        group_eval<-1, 0, 1, 2, 3>(pd,p0,p1,p2,x,edge,ryy,TT,aW,aR,aG,aB,aD);
        group_eval< 4, 5, 6>      (pd,p0,p1,p2,x,edge,ryy,TT,aW,aR,aG,aB,aD);
    }

#pragma unroll
    for (int k=0;k<TY;++k) {
        const int y = y0 + k;
        const float inv = __builtin_amdgcn_rcpf(aW[k]);  // aW >= ~0.0139 always
        const size_t o = (size_t)y*WW + x;
        out[(size_t)(b*3+0)*HWSZ + o] = aR[k]*inv;
        out[(size_t)(b*3+1)*HWSZ + o] = aG[k]*inv;
        out[(size_t)(b*3+2)*HWSZ + o] = aB[k]*inv;
        out[DD_OFF + (size_t)b*HWSZ + o] = aD[k];
    }
}

extern "C" void kernel_launch(void* const* d_in, const int* in_sizes, int n_in,
                              void* d_out, int out_size, void* d_ws, size_t ws_size,
                              hipStream_t stream)
{
    const float* img  = (const float*)d_in[0];
    const float* defo = (const float*)d_in[1];
    float* out = (float*)d_out;
    bokeh_kernel<<<dim3(WW/64, HH/(4*TY), BB), dim3(256,1,1), 0, stream>>>(img, defo, out);
}